// Round 3
// baseline (396.124 us; speedup 1.0000x reference)
//
#include <hip/hip_runtime.h>
#include <hip/hip_cooperative_groups.h>
#include <hip/hip_bf16.h>

namespace cg = cooperative_groups;

// Problem constants (B,S,H,Q,D,C) = (8,512,768,64,256,2)
#define B_ 8
#define S_ 512
#define H_ 768
#define Q_ 64
#define D_ 256

// ============================================================================
// Fused cooperative kernel: grid = 640 blocks x 256 threads (all co-resident)
// P1 norms+lens+zero-out | P2 qbar+query_avg | P3 doc weights | P4 doc sum |
// P5 mlp1 + fused logits (atomicAdd)
// ============================================================================
__global__ __launch_bounds__(256) void k_fused(
        const float* __restrict__ feats,
        const int* __restrict__ aidx,
        const int* __restrict__ bidx,
        const float* __restrict__ W1,
        const float* __restrict__ b1,
        const float* __restrict__ W2,
        const float* __restrict__ b2,
        float* __restrict__ invn /* [B*Q | B*D] */,
        float* __restrict__ lens /* [2*B] */,
        float* __restrict__ qbar /* [B*H] */,
        float* __restrict__ feat /* [B*2H] */,
        float* __restrict__ w    /* [B*D] */,
        float* __restrict__ out  /* [B*2] */) {
    cg::grid_group grid = cg::this_grid();
    const int bk = blockIdx.x;
    const int t  = threadIdx.x;
    const int wv = t >> 6, lane = t & 63;

    __shared__ union {
        struct { int cnt[4]; } p1;
        struct { int idx[Q_]; float inv[Q_]; float red0[4][64]; float red1[4][64]; } p2;
        struct { float w[D_]; int i[D_]; float red[4][64]; } p4;
        struct { float f[2 * H_]; float red[4][64]; } p5;
    } sm;

    // ---------------- P1: inverse norms for all 2560 gathered rows ----------
    {
        int r = bk * 4 + wv;                  // 0..2559
        int b = r / (Q_ + D_);
        int i = r % (Q_ + D_);
        int idx; float* outp;
        if (i < Q_) {
            idx = aidx[b * Q_ + i];
            outp = invn + b * Q_ + i;
        } else {
            int j = i - Q_;
            idx = bidx[b * D_ + j];
            outp = invn + B_ * Q_ + b * D_ + j;
        }
        const float4* row4 = (const float4*)(feats + ((size_t)b * S_ + idx) * H_);
        float ss = 0.f;
#pragma unroll
        for (int k = 0; k < 3; ++k) {
            float4 v = row4[lane + k * 64];
            ss += v.x * v.x + v.y * v.y + v.z * v.z + v.w * v.w;
        }
        for (int off = 32; off; off >>= 1) ss += __shfl_xor(ss, off, 64);
        if (lane == 0) *outp = 1.f / fmaxf(sqrtf(ss), 1e-8f);
    }
    if (bk < B_) {                            // lens for batch bk
        int b = bk;
        unsigned long long mb = __ballot(bidx[b * D_ + wv * 64 + lane] > 0);
        if (lane == 0) sm.p1.cnt[wv] = __popcll(mb);
        if (wv == 0) {
            unsigned long long ma = __ballot(aidx[b * Q_ + lane] > 0);
            if (lane == 0) lens[b] = (float)__popcll(ma);
        }
        __syncthreads();
        if (t == 0)
            lens[B_ + b] = (float)(sm.p1.cnt[0] + sm.p1.cnt[1] + sm.p1.cnt[2] + sm.p1.cnt[3]);
    }
    if (bk == B_ && t < 2 * B_) out[t] = 0.f; // zero logits for P5 atomics

    grid.sync();

    // ---------------- P2: qbar + query_avg (blocks 0..95) -------------------
    if (bk < 96) {
        int b = bk / 12, hc = bk % 12;
        if (t < Q_) {
            sm.p2.idx[t] = aidx[b * Q_ + t];
            sm.p2.inv[t] = invn[b * Q_ + t];
        }
        __syncthreads();
        int h = hc * 64 + lane;
        float pb = 0.f, pa = 0.f;
#pragma unroll
        for (int q = wv * 16; q < wv * 16 + 16; ++q) {
            int idx = sm.p2.idx[q];
            if (idx > 0) {
                float f = feats[((size_t)b * S_ + idx) * H_ + h];
                pb += f * sm.p2.inv[q];
                pa += f;
            }
        }
        sm.p2.red0[wv][lane] = pb;
        sm.p2.red1[wv][lane] = pa;
        __syncthreads();
        if (t < 64) {
            int h2 = hc * 64 + t;
            float qb = sm.p2.red0[0][t] + sm.p2.red0[1][t] + sm.p2.red0[2][t] + sm.p2.red0[3][t];
            float qa = sm.p2.red1[0][t] + sm.p2.red1[1][t] + sm.p2.red1[2][t] + sm.p2.red1[3][t];
            qbar[b * H_ + h2] = qb;
            feat[b * 2 * H_ + h2] = qa / lens[b];
        }
    }

    grid.sync();

    // ---------------- P3: doc weights w[b,d] (blocks 0..511) ----------------
    if (bk < 512) {
        int gw = bk * 4 + wv;                 // 0..2047
        int b = gw >> 8;
        int d = gw & 255;
        int idx = bidx[b * D_ + d];
        const float4* row4 = (const float4*)(feats + ((size_t)b * S_ + idx) * H_);
        const float4* q4 = (const float4*)(qbar + b * H_);
        float dot = 0.f;
#pragma unroll
        for (int k = 0; k < 3; ++k) {
            float4 v = row4[lane + k * 64];
            float4 qv = q4[lane + k * 64];
            dot += v.x * qv.x + v.y * qv.y + v.z * qv.z + v.w * qv.w;
        }
        for (int off = 32; off; off >>= 1) dot += __shfl_xor(dot, off, 64);
        if (lane == 0) {
            float scale = 1.f / (lens[b] * lens[B_ + b]);
            w[b * D_ + d] = (idx > 0) ? dot * invn[B_ * Q_ + b * D_ + d] * scale : 0.f;
        }
    }

    grid.sync();

    // ---------------- P4: query_based_doc = weighted row sum (blocks 0..95) -
    if (bk < 96) {
        int b = bk / 12, hc = bk % 12;
        sm.p4.w[t] = w[b * D_ + t];
        sm.p4.i[t] = bidx[b * D_ + t];
        __syncthreads();
        int h = hc * 64 + lane;
        float acc = 0.f;
#pragma unroll 8
        for (int d = wv * 64; d < wv * 64 + 64; ++d) {
            acc += sm.p4.w[d] * feats[((size_t)b * S_ + sm.p4.i[d]) * H_ + h];
        }
        sm.p4.red[wv][lane] = acc;
        __syncthreads();
        if (t < 64) {
            feat[b * 2 * H_ + H_ + hc * 64 + t] =
                sm.p4.red[0][t] + sm.p4.red[1][t] + sm.p4.red[2][t] + sm.p4.red[3][t];
        }
    }

    grid.sync();

    // ---------------- P5: hidden = relu(feat@W1+b1); logits atomics ---------
    if (bk < 96) {
        int b = bk / 12, hc = bk % 12;
        for (int i = t; i < 2 * H_; i += 256) sm.p5.f[i] = feat[b * 2 * H_ + i];
        __syncthreads();
        int h = hc * 64 + lane;
        const float* wp = W1 + (size_t)(wv * 384) * H_ + h;
        const float* fp = sm.p5.f + wv * 384;
        float acc = 0.f;
#pragma unroll 8
        for (int k = 0; k < 384; ++k) acc += fp[k] * wp[(size_t)k * H_];
        sm.p5.red[wv][lane] = acc;
        __syncthreads();
        if (t < 64) {
            int h2 = hc * 64 + t;
            float v = sm.p5.red[0][t] + sm.p5.red[1][t] + sm.p5.red[2][t] + sm.p5.red[3][t] + b1[h2];
            v = fmaxf(v, 0.f);
            float p0 = v * W2[h2 * 2 + 0];
            float p1 = v * W2[h2 * 2 + 1];
            for (int off = 32; off; off >>= 1) {
                p0 += __shfl_xor(p0, off, 64);
                p1 += __shfl_xor(p1, off, 64);
            }
            if (t == 0) {
                atomicAdd(&out[b * 2 + 0], p0 + (hc == 0 ? b2[0] : 0.f));
                atomicAdd(&out[b * 2 + 1], p1 + (hc == 0 ? b2[1] : 0.f));
            }
        }
    }
}

// ============================================================================
// Fallback path (R2 pipeline) in case cooperative launch is rejected
// ============================================================================
__global__ __launch_bounds__(256) void k_norms_lens(
        const float* __restrict__ feats, const int* __restrict__ aidx,
        const int* __restrict__ bidx, float* __restrict__ invn,
        float* __restrict__ lens) {
    int t = threadIdx.x;
    int wave = t >> 6, lane = t & 63;
    if (blockIdx.x < 640) {
        int r = blockIdx.x * 4 + wave;
        int b = r / (Q_ + D_);
        int i = r % (Q_ + D_);
        int idx; float* outp;
        if (i < Q_) { idx = aidx[b * Q_ + i]; outp = invn + b * Q_ + i; }
        else { int j = i - Q_; idx = bidx[b * D_ + j]; outp = invn + B_ * Q_ + b * D_ + j; }
        const float4* row4 = (const float4*)(feats + ((size_t)b * S_ + idx) * H_);
        float ss = 0.f;
#pragma unroll
        for (int k = 0; k < 3; ++k) {
            float4 v = row4[lane + k * 64];
            ss += v.x * v.x + v.y * v.y + v.z * v.z + v.w * v.w;
        }
        for (int off = 32; off; off >>= 1) ss += __shfl_xor(ss, off, 64);
        if (lane == 0) *outp = 1.f / fmaxf(sqrtf(ss), 1e-8f);
    } else {
        int b = blockIdx.x - 640;
        __shared__ int cnt[4];
        unsigned long long mb = __ballot(bidx[b * D_ + wave * 64 + lane] > 0);
        if (lane == 0) cnt[wave] = __popcll(mb);
        if (wave == 0) {
            unsigned long long ma = __ballot(aidx[b * Q_ + lane] > 0);
            if (lane == 0) lens[b] = (float)__popcll(ma);
        }
        __syncthreads();
        if (t == 0) lens[B_ + b] = (float)(cnt[0] + cnt[1] + cnt[2] + cnt[3]);
    }
}

__global__ __launch_bounds__(256) void k_qbar(
        const float* __restrict__ feats, const int* __restrict__ aidx,
        const float* __restrict__ invn, const float* __restrict__ lens,
        float* __restrict__ qbar, float* __restrict__ feat) {
    int b = blockIdx.x / 12, hc = blockIdx.x % 12;
    int t = threadIdx.x, lane = t & 63, qg = t >> 6;
    __shared__ int s_idx[Q_];
    __shared__ float s_inv[Q_];
    __shared__ float red0[4][64], red1[4][64];
    if (t < Q_) { s_idx[t] = aidx[b * Q_ + t]; s_inv[t] = invn[b * Q_ + t]; }
    __syncthreads();
    int h = hc * 64 + lane;
    float pb = 0.f, pa = 0.f;
#pragma unroll
    for (int q = qg * 16; q < qg * 16 + 16; ++q) {
        int idx = s_idx[q];
        if (idx > 0) {
            float f = feats[((size_t)b * S_ + idx) * H_ + h];
            pb += f * s_inv[q]; pa += f;
        }
    }
    red0[qg][lane] = pb; red1[qg][lane] = pa;
    __syncthreads();
    if (t < 64) {
        int h2 = hc * 64 + t;
        qbar[b * H_ + h2] = red0[0][t] + red0[1][t] + red0[2][t] + red0[3][t];
        feat[b * 2 * H_ + h2] = (red1[0][t] + red1[1][t] + red1[2][t] + red1[3][t]) / lens[b];
    }
}

__global__ __launch_bounds__(256) void k_docw(
        const float* __restrict__ feats, const int* __restrict__ bidx,
        const float* __restrict__ invn, const float* __restrict__ lens,
        const float* __restrict__ qbar, float* __restrict__ w) {
    int t = threadIdx.x, lane = t & 63;
    int gw = blockIdx.x * 4 + (t >> 6);
    int b = gw >> 8, d = gw & 255;
    int idx = bidx[b * D_ + d];
    const float4* row4 = (const float4*)(feats + ((size_t)b * S_ + idx) * H_);
    const float4* q4 = (const float4*)(qbar + b * H_);
    float dot = 0.f;
#pragma unroll
    for (int k = 0; k < 3; ++k) {
        float4 v = row4[lane + k * 64];
        float4 qv = q4[lane + k * 64];
        dot += v.x * qv.x + v.y * qv.y + v.z * qv.z + v.w * qv.w;
    }
    for (int off = 32; off; off >>= 1) dot += __shfl_xor(dot, off, 64);
    if (lane == 0) {
        float scale = 1.f / (lens[b] * lens[B_ + b]);
        w[b * D_ + d] = (idx > 0) ? dot * invn[B_ * Q_ + b * D_ + d] * scale : 0.f;
    }
}

__global__ __launch_bounds__(256) void k_docsum(
        const float* __restrict__ feats, const int* __restrict__ bidx,
        const float* __restrict__ w, float* __restrict__ feat) {
    int b = blockIdx.x / 12, hc = blockIdx.x % 12;
    int t = threadIdx.x, lane = t & 63, dg = t >> 6;
    __shared__ float s_w[D_];
    __shared__ int s_i[D_];
    __shared__ float red[4][64];
    s_w[t] = w[b * D_ + t];
    s_i[t] = bidx[b * D_ + t];
    __syncthreads();
    int h = hc * 64 + lane;
    float acc = 0.f;
#pragma unroll 8
    for (int d = dg * 64; d < dg * 64 + 64; ++d)
        acc += s_w[d] * feats[((size_t)b * S_ + s_i[d]) * H_ + h];
    red[dg][lane] = acc;
    __syncthreads();
    if (t < 64)
        feat[b * 2 * H_ + H_ + hc * 64 + t] = red[0][t] + red[1][t] + red[2][t] + red[3][t];
}

__global__ __launch_bounds__(256) void k_mlp1(
        const float* __restrict__ feat, const float* __restrict__ W1,
        const float* __restrict__ b1, float* __restrict__ hidden) {
    int b = blockIdx.x / 12, hc = blockIdx.x % 12;
    int t = threadIdx.x, lane = t & 63, kg = t >> 6;
    __shared__ float s_f[2 * H_];
    __shared__ float red[4][64];
    for (int i = t; i < 2 * H_; i += 256) s_f[i] = feat[b * 2 * H_ + i];
    __syncthreads();
    int h = hc * 64 + lane;
    const float* wp = W1 + (size_t)(kg * 384) * H_ + h;
    const float* fp = s_f + kg * 384;
    float acc = 0.f;
#pragma unroll 8
    for (int k = 0; k < 384; ++k) acc += fp[k] * wp[(size_t)k * H_];
    red[kg][lane] = acc;
    __syncthreads();
    if (t < 64) {
        int h2 = hc * 64 + t;
        hidden[b * H_ + h2] = fmaxf(red[0][t] + red[1][t] + red[2][t] + red[3][t] + b1[h2], 0.f);
    }
}

__global__ __launch_bounds__(256) void k_mlp2(
        const float* __restrict__ hidden, const float* __restrict__ W2,
        const float* __restrict__ b2, float* __restrict__ out) {
    int b = blockIdx.x;
    int t = threadIdx.x, lane = t & 63, wave = t >> 6;
    float a0 = 0.f, a1 = 0.f;
#pragma unroll
    for (int k = 0; k < 3; ++k) {
        int h = t + k * 256;
        float v = hidden[b * H_ + h];
        a0 += v * W2[h * 2 + 0];
        a1 += v * W2[h * 2 + 1];
    }
    for (int off = 32; off; off >>= 1) {
        a0 += __shfl_xor(a0, off, 64);
        a1 += __shfl_xor(a1, off, 64);
    }
    __shared__ float r0[4], r1[4];
    if (lane == 0) { r0[wave] = a0; r1[wave] = a1; }
    __syncthreads();
    if (t == 0) {
        out[b * 2 + 0] = r0[0] + r0[1] + r0[2] + r0[3] + b2[0];
        out[b * 2 + 1] = r1[0] + r1[1] + r1[2] + r1[3] + b2[1];
    }
}

extern "C" void kernel_launch(void* const* d_in, const int* in_sizes, int n_in,
                              void* d_out, int out_size, void* d_ws, size_t ws_size,
                              hipStream_t stream) {
    const float* feats = (const float*)d_in[0];
    const int*   aidx  = (const int*)d_in[1];
    const int*   bidx  = (const int*)d_in[2];
    const float* W1    = (const float*)d_in[3];
    const float* b1    = (const float*)d_in[4];
    const float* W2    = (const float*)d_in[5];
    const float* b2    = (const float*)d_in[6];
    float* out = (float*)d_out;

    // workspace layout (floats)
    float* ws = (float*)d_ws;
    float* invn   = ws;                          // B*(Q+D) = 2560
    float* lens   = invn + B_ * (Q_ + D_);       // 16
    float* qbar   = lens + 2 * B_;               // 6144 (16B-aligned offset)
    float* feat   = qbar + B_ * H_;              // 12288
    float* w      = feat + B_ * 2 * H_;          // 2048
    float* hidden = w + B_ * D_;                 // 6144 (fallback only)

    void* args[] = {
        (void*)&feats, (void*)&aidx, (void*)&bidx,
        (void*)&W1, (void*)&b1, (void*)&W2, (void*)&b2,
        (void*)&invn, (void*)&lens, (void*)&qbar, (void*)&feat, (void*)&w,
        (void*)&out
    };
    hipError_t e = hipLaunchCooperativeKernel((const void*)k_fused,
                                              dim3(640), dim3(256),
                                              args, 0, stream);
    if (e != hipSuccess) {
        // Fallback: 6-kernel pipeline (same math)
        k_norms_lens<<<648, 256, 0, stream>>>(feats, aidx, bidx, invn, lens);
        k_qbar<<<96, 256, 0, stream>>>(feats, aidx, invn, lens, qbar, feat);
        k_docw<<<512, 256, 0, stream>>>(feats, bidx, invn, lens, qbar, w);
        k_docsum<<<96, 256, 0, stream>>>(feats, bidx, w, feat);
        k_mlp1<<<96, 256, 0, stream>>>(feat, W1, b1, hidden);
        k_mlp2<<<B_, 256, 0, stream>>>(hidden, W2, b2, out);
    }
}

// Round 4
// 113.287 us; speedup vs baseline: 3.4967x; 3.4967x over previous
//
#include <hip/hip_runtime.h>
#include <hip/hip_bf16.h>

// Problem constants (B,S,H,Q,D,C) = (8,512,768,64,256,2)
#define B_ 8
#define S_ 512
#define H_ 768
#define Q_ 64
#define D_ 256

// ws layout (floats): qbar[6144] | qa[6144] | w[2048] | hidden[6144] | counter+pad[256]
#define WS_QBAR   0
#define WS_QA     (B_ * H_)            // 6144
#define WS_W      (2 * B_ * H_)        // 12288
#define WS_HIDDEN (2 * B_ * H_ + B_ * D_)  // 14336
#define WS_CNT    (WS_HIDDEN + B_ * H_)    // 20480
#define ZERO_N    (B_ * H_ + 256)          // 6400 floats: hidden + counter + pad

// ============================================================================
// K1: per (b, h-chunk): alen + q-row inverse norms (in-block) + qbar + query_avg
// grid: B*12 = 96 blocks, 256 threads
// ============================================================================
__global__ __launch_bounds__(256) void k_qbar(
        const float* __restrict__ feats,
        const int* __restrict__ aidx,
        float* __restrict__ ws) {
    float* qbar = ws + WS_QBAR;
    float* qa   = ws + WS_QA;
    int b = blockIdx.x / 12, hc = blockIdx.x % 12;
    int t = threadIdx.x, wv = t >> 6, lane = t & 63;
    __shared__ float s_alen;
    __shared__ float red0[4][64], red1[4][64];
    if (wv == 0) {
        unsigned long long ma = __ballot(aidx[b * Q_ + lane] > 0);
        if (lane == 0) s_alen = (float)__popcll(ma);
    }
    int hh = hc * 64 + lane;
    float pb = 0.f, pa = 0.f;
#pragma unroll 2
    for (int q = wv * 16; q < wv * 16 + 16; ++q) {
        int idx = aidx[b * Q_ + q];
        const float* row = feats + ((size_t)b * S_ + idx) * H_;
        const float4* row4 = (const float4*)row;
        float ss = 0.f;
#pragma unroll
        for (int k = 0; k < 3; ++k) {
            float4 v = row4[lane + k * 64];
            ss += v.x * v.x + v.y * v.y + v.z * v.z + v.w * v.w;
        }
        for (int off = 32; off; off >>= 1) ss += __shfl_xor(ss, off, 64);
        float inv = 1.f / fmaxf(sqrtf(ss), 1e-8f);
        float f = row[hh];
        if (idx > 0) { pb += f * inv; pa += f; }
    }
    red0[wv][lane] = pb;
    red1[wv][lane] = pa;
    __syncthreads();
    if (t < 64) {
        int h2 = hc * 64 + t;
        float qb = red0[0][t] + red0[1][t] + red0[2][t] + red0[3][t];
        float qv = red1[0][t] + red1[1][t] + red1[2][t] + red1[3][t];
        qbar[b * H_ + h2] = qb;
        qa[b * H_ + h2] = qv / s_alen;
    }
}

// ============================================================================
// K2: per (b,d) wave: w[b,d] = mask * dot(qbar, f_d) * invnorm(f_d) / (alen*blen)
//     (d-norm folded into the same row pass). Blocks 0..24 zero hidden+counter.
// grid: B*D/4 = 512 blocks, 256 threads
// ============================================================================
__global__ __launch_bounds__(256) void k_docw(
        const float* __restrict__ feats,
        const int* __restrict__ aidx,
        const int* __restrict__ bidx,
        float* __restrict__ ws) {
    const float* qbar = ws + WS_QBAR;
    float* w = ws + WS_W;
    float* zero_region = ws + WS_HIDDEN;
    int t = threadIdx.x, wv = t >> 6, lane = t & 63;
    if (blockIdx.x < 25) {
        zero_region[blockIdx.x * 256 + t] = 0.f;   // 6400 >= 6144+1
    }
    int gw = blockIdx.x * 4 + wv;                  // 0..2047
    int b = gw >> 8, d = gw & 255;
    __shared__ int cnt[4];
    __shared__ float s_alen;
    unsigned long long mb = __ballot(bidx[b * D_ + wv * 64 + lane] > 0);
    if (lane == 0) cnt[wv] = __popcll(mb);
    if (wv == 0) {
        unsigned long long ma = __ballot(aidx[b * Q_ + lane] > 0);
        if (lane == 0) s_alen = (float)__popcll(ma);
    }
    __syncthreads();
    float blen = (float)(cnt[0] + cnt[1] + cnt[2] + cnt[3]);
    int idx = bidx[b * D_ + d];
    const float4* row4 = (const float4*)(feats + ((size_t)b * S_ + idx) * H_);
    const float4* q4 = (const float4*)(qbar + b * H_);
    float dqf = 0.f, dff = 0.f;
#pragma unroll
    for (int k = 0; k < 3; ++k) {
        float4 v = row4[lane + k * 64];
        float4 qv = q4[lane + k * 64];
        dqf += v.x * qv.x + v.y * qv.y + v.z * qv.z + v.w * qv.w;
        dff += v.x * v.x + v.y * v.y + v.z * v.z + v.w * v.w;
    }
    for (int off = 32; off; off >>= 1) {
        dqf += __shfl_xor(dqf, off, 64);
        dff += __shfl_xor(dff, off, 64);
    }
    if (lane == 0) {
        float inv = 1.f / fmaxf(sqrtf(dff), 1e-8f);
        float scale = 1.f / (s_alen * blen);
        w[b * D_ + d] = (idx > 0) ? dqf * inv * scale : 0.f;
    }
}

// ============================================================================
// K3: per (b, h-chunk): qbd chunk (weighted row sum) -> partial GEMV of both
//     W1 halves (128 k-rows) -> atomicAdd hidden; last block: relu+logits.
// grid: B*12 = 96 blocks, 256 threads
// ============================================================================
__global__ __launch_bounds__(256) void k_docsum_mlp(
        const float* __restrict__ feats,
        const int* __restrict__ bidx,
        const float* __restrict__ W1,
        const float* __restrict__ b1,
        const float* __restrict__ W2,
        const float* __restrict__ b2,
        float* __restrict__ ws,
        float* __restrict__ out) {
    const float* qa = ws + WS_QA;
    const float* w  = ws + WS_W;
    float* hidden   = ws + WS_HIDDEN;
    int* counter    = (int*)(ws + WS_CNT);
    int b = blockIdx.x / 12, hc = blockIdx.x % 12;
    int t = threadIdx.x, wv = t >> 6, lane = t & 63;
    __shared__ float s_w[D_];
    __shared__ int   s_i[D_];
    __shared__ float s_k[128];        // [0:64]=qa chunk, [64:128]=qbd chunk
    __shared__ float red[4][64];
    __shared__ int   s_flag;
    s_w[t] = w[b * D_ + t];
    s_i[t] = bidx[b * D_ + t];
    if (t < 64) s_k[t] = qa[b * H_ + hc * 64 + t];
    __syncthreads();
    int hh = hc * 64 + lane;
    float acc = 0.f;
#pragma unroll 8
    for (int d = wv * 64; d < wv * 64 + 64; ++d)
        acc += s_w[d] * feats[((size_t)b * S_ + s_i[d]) * H_ + hh];
    red[wv][lane] = acc;
    __syncthreads();
    if (t < 64) s_k[64 + t] = red[0][t] + red[1][t] + red[2][t] + red[3][t];
    __syncthreads();
    // partial GEMV: k rows {hc*64..+64} (qa) and {768+hc*64..+64} (qbd)
    const float* Wtop = W1 + (size_t)(hc * 64) * H_;
    const float* Wbot = W1 + (size_t)(H_ + hc * 64) * H_;
    float h0 = 0.f, h1 = 0.f, h2 = 0.f;
#pragma unroll 4
    for (int i = 0; i < 64; ++i) {
        float ka = s_k[i], kb = s_k[64 + i];
        const float* r1 = Wtop + (size_t)i * H_;
        const float* r2 = Wbot + (size_t)i * H_;
        h0 += ka * r1[t]       + kb * r2[t];
        h1 += ka * r1[t + 256] + kb * r2[t + 256];
        h2 += ka * r1[t + 512] + kb * r2[t + 512];
    }
    atomicAdd(&hidden[b * H_ + t],       h0);
    atomicAdd(&hidden[b * H_ + t + 256], h1);
    atomicAdd(&hidden[b * H_ + t + 512], h2);
    __threadfence();
    __syncthreads();
    if (t == 0) {
        int old = atomicAdd(counter, 1);
        s_flag = (old == 95);
    }
    __syncthreads();
    if (s_flag) {
        __threadfence();
        // epilogue: wave wv handles batches 2wv, 2wv+1
        for (int bb = wv * 2; bb < wv * 2 + 2; ++bb) {
            float a0 = 0.f, a1 = 0.f;
#pragma unroll
            for (int k = 0; k < 12; ++k) {
                int h = lane + k * 64;
                float hv = __hip_atomic_load(&hidden[bb * H_ + h],
                                             __ATOMIC_RELAXED,
                                             __HIP_MEMORY_SCOPE_AGENT);
                float v = fmaxf(hv + b1[h], 0.f);
                a0 += v * W2[h * 2 + 0];
                a1 += v * W2[h * 2 + 1];
            }
            for (int off = 32; off; off >>= 1) {
                a0 += __shfl_xor(a0, off, 64);
                a1 += __shfl_xor(a1, off, 64);
            }
            if (lane == 0) {
                out[bb * 2 + 0] = a0 + b2[0];
                out[bb * 2 + 1] = a1 + b2[1];
            }
        }
    }
}

extern "C" void kernel_launch(void* const* d_in, const int* in_sizes, int n_in,
                              void* d_out, int out_size, void* d_ws, size_t ws_size,
                              hipStream_t stream) {
    const float* feats = (const float*)d_in[0];
    const int*   aidx  = (const int*)d_in[1];
    const int*   bidx  = (const int*)d_in[2];
    const float* W1    = (const float*)d_in[3];
    const float* b1    = (const float*)d_in[4];
    const float* W2    = (const float*)d_in[5];
    const float* b2    = (const float*)d_in[6];
    float* out = (float*)d_out;
    float* ws = (float*)d_ws;

    k_qbar<<<96, 256, 0, stream>>>(feats, aidx, ws);
    k_docw<<<512, 256, 0, stream>>>(feats, aidx, bidx, ws);
    k_docsum_mlp<<<96, 256, 0, stream>>>(feats, bidx, W1, b1, W2, b2, ws, out);
}